// Round 8
// baseline (109.630 us; speedup 1.0000x reference)
//
#include <hip/hip_runtime.h>

typedef __attribute__((ext_vector_type(8))) short short8;
typedef __attribute__((ext_vector_type(4))) float f32x4;
typedef __attribute__((ext_vector_type(16))) float f32x16;

// B=4, C=256, pooled N=4096, kc=vc=128, oc=256
static constexpr size_t OFF_SIGMA = 0;
static constexpr size_t OFF_ML    = 256;                        // float[8][16384] row-sums
static constexpr size_t OFF_QKT   = 1048576;                    // bf16 [4][4096][128] (col-swizzled)
static constexpr size_t OFF_V     = OFF_QKT + 4194304;          // bf16 [4][128][4096] (64-tile swizzled)
static constexpr size_t OFF_WCAT  = OFF_V + 4194304;            // bf16 Ww[256][128] | Wk[128][256] | Wv[128][256]
static constexpr size_t OFF_XFB   = OFF_WCAT + 196608;          // bf16 [4*256][4096]
static constexpr size_t OFF_PC    = OFF_XFB;                    // bf16 [8][16384][128] (aliases xfb; xfb dead by attn)

__device__ inline unsigned short f2bf(float f) {
  unsigned int u = __float_as_uint(f);
  unsigned int r = u + 0x7fffu + ((u >> 16) & 1u);
  return (unsigned short)(r >> 16);
}
__device__ inline float bf2f(unsigned short s) {
  return __uint_as_float(((unsigned int)s) << 16);
}
__device__ inline unsigned int cvtpk_bf16(float a, float b) {
  unsigned int r;
  asm("v_cvt_pk_bf16_f32 %0, %1, %2" : "=v"(r) : "v"(a), "v"(b));
  return r;
}

// ---------------- K1: maxpool3d(2) -> xfb bf16 [4,256,4096] ----------------
__launch_bounds__(256)
__global__ void k_maxpool(const float* __restrict__ x, unsigned short* __restrict__ xfb) {
  int idx = blockIdx.x * 256 + threadIdx.x;      // 2 outputs per thread
  int n2 = idx & 2047;
  int bc = idx >> 11;
  int d2p = n2 & 7, d1 = (n2 >> 3) & 15, d0 = n2 >> 7;
  const float* p = x + (size_t)bc * 32768 + (size_t)d0 * 2048 + d1 * 64 + d2p * 4;
  float4 a = *(const float4*)(p);
  float4 b = *(const float4*)(p + 32);
  float4 c = *(const float4*)(p + 1024);
  float4 e = *(const float4*)(p + 1056);
  float o0 = fmaxf(fmaxf(fmaxf(a.x, a.y), fmaxf(b.x, b.y)),
                   fmaxf(fmaxf(c.x, c.y), fmaxf(e.x, e.y)));
  float o1 = fmaxf(fmaxf(fmaxf(a.z, a.w), fmaxf(b.z, b.w)),
                   fmaxf(fmaxf(c.z, c.w), fmaxf(e.z, e.w)));
  unsigned int pk = (unsigned int)f2bf(o0) | ((unsigned int)f2bf(o1) << 16);
  *(unsigned int*)(xfb + (size_t)bc * 4096 + n2 * 2) = pk;
}

// ---------------- K2: spectral-norm sigma ----------------------------------
__global__ void k_sigma(const float* __restrict__ Wk, const float* __restrict__ u,
                        float* __restrict__ sig) {
  __shared__ float vsh[256];
  __shared__ float red[256];
  __shared__ float ush[128];
  int t = threadIdx.x;
  if (t < 128) ush[t] = u[t];
  __syncthreads();
  float acc = 0.f;
  for (int k = 0; k < 128; k++) acc += Wk[(size_t)k * 256 + t] * ush[k];
  vsh[t] = acc;
  red[t] = acc * acc;
  __syncthreads();
  for (int s = 128; s > 0; s >>= 1) { if (t < s) red[t] += red[t + s]; __syncthreads(); }
  float nrm = sqrtf(red[0]) + 1e-12f;
  float vn = vsh[t] / nrm;
  __syncthreads();
  vsh[t] = vn;
  __syncthreads();
  float acc2 = 0.f;
  if (t < 128) {
    for (int c = 0; c < 256; c++) acc2 += Wk[(size_t)t * 256 + c] * vsh[c];
  }
  red[t] = (t < 128) ? acc2 * acc2 : 0.f;
  __syncthreads();
  for (int s = 128; s > 0; s >>= 1) { if (t < s) red[t] += red[t + s]; __syncthreads(); }
  if (t == 0) {
    float s2v = red[0];
    sig[0] = s2v / (sqrtf(s2v) + 1e-12f);
  }
}

// ---------------- K2b: Ww|Wk|Wv f32 -> bf16 wcat ---------------------------
__launch_bounds__(256)
__global__ void k_prep(const float* __restrict__ Ww, const float* __restrict__ Wk,
                       const float* __restrict__ Wv, unsigned short* __restrict__ wcat) {
  int i = (blockIdx.x * 256 + threadIdx.x) * 4;       // 98304 total
  const float* src = (i < 32768) ? (Ww + i) : (i < 65536) ? (Wk + i - 32768)
                                                          : (Wv + i - 65536);
  float4 w = *(const float4*)src;
  unsigned int lo = (unsigned int)f2bf(w.x) | ((unsigned int)f2bf(w.y) << 16);
  unsigned int hi = (unsigned int)f2bf(w.z) | ((unsigned int)f2bf(w.w) << 16);
  *(uint2*)(wcat + i) = make_uint2(lo, hi);
}

// ---------------- K3: fused projections via MFMA ---------------------------
__launch_bounds__(256)
__global__ void k_qkv(const unsigned short* __restrict__ xfb,
                      const unsigned short* __restrict__ wcat,
                      const float* __restrict__ bk, const float* __restrict__ bv,
                      const float* __restrict__ sig,
                      unsigned short* __restrict__ qkT, unsigned short* __restrict__ vws) {
  __shared__ __align__(16) unsigned short Bl[64 * 64];   // [n][64k], kg-XOR swizzle
  int bid = blockIdx.x;
  int nt = bid & 63, b = bid >> 6;
  int n0 = nt * 64;
  int t = threadIdx.x, wid = t >> 6, lane = t & 63, g = lane >> 4, lr = lane & 15;
  int R0 = wid * 64;
  bool isq = (wid < 2);
  const unsigned short* wb = isq ? (wcat + 32768 + (size_t)R0 * 256)
                                 : (wcat + 65536 + (size_t)(R0 - 128) * 256);
  f32x4 acc[4][4];
#pragma unroll
  for (int i = 0; i < 4; i++)
#pragma unroll
    for (int j = 0; j < 4; j++) acc[i][j] = (f32x4){0.f, 0.f, 0.f, 0.f};

  short8 st[2];
#pragma unroll
  for (int i = 0; i < 2; i++) {
    int gid = i * 256 + t;
    st[i] = *(const short8*)(xfb + ((size_t)(b * 256 + (gid >> 3))) * 4096 +
                             n0 + (gid & 7) * 8);
  }

#pragma unroll 1
  for (int ks4 = 0; ks4 < 4; ks4++) {
    int k0 = ks4 * 64;
    __syncthreads();
#pragma unroll
    for (int i = 0; i < 2; i++) {
      int gid = i * 256 + t;
      int c = gid >> 3, nch = gid & 7;
#pragma unroll
      for (int j = 0; j < 8; j++) {
        int n = nch * 8 + j;
        Bl[n * 64 + (((c >> 3) ^ (n & 7)) << 3) + (c & 7)] = (unsigned short)st[i][j];
      }
    }
    if (ks4 < 3) {
#pragma unroll
      for (int i = 0; i < 2; i++) {
        int gid = i * 256 + t;
        st[i] = *(const short8*)(xfb + ((size_t)(b * 256 + k0 + 64 + (gid >> 3))) * 4096 +
                                 n0 + (gid & 7) * 8);
      }
    }
    __syncthreads();
#pragma unroll
    for (int ks2 = 0; ks2 < 2; ks2++) {
      short8 af[4], bf[4];
#pragma unroll
      for (int ot = 0; ot < 4; ot++)
        af[ot] = *(const short8*)(wb + (size_t)(ot * 16 + lr) * 256 + k0 + ks2 * 32 + g * 8);
#pragma unroll
      for (int nt2 = 0; nt2 < 4; nt2++) {
        int n = nt2 * 16 + lr;
        bf[nt2] = *(const short8*)(Bl + n * 64 + (((ks2 * 4 + g) ^ (n & 7)) << 3));
      }
#pragma unroll
      for (int ot = 0; ot < 4; ot++)
#pragma unroll
        for (int nt2 = 0; nt2 < 4; nt2++)
          acc[ot][nt2] = __builtin_amdgcn_mfma_f32_16x16x32_bf16(af[ot], bf[nt2],
                                                                 acc[ot][nt2], 0, 0, 0);
    }
  }

  if (isq) {
    float inv_s = 1.0f / sig[0];
#pragma unroll
    for (int ot = 0; ot < 4; ot++)
#pragma unroll
      for (int rr = 0; rr < 4; rr++) {
        int d = R0 + ot * 16 + g * 4 + rr;
        float bias = bk[d];
#pragma unroll
        for (int nt2 = 0; nt2 < 4; nt2++) {
          int n = n0 + nt2 * 16 + lr;
          float val = acc[ot][nt2][rr] * inv_s + bias;
          int ds = ((((d >> 3) ^ (n & 7)) & 15) << 3) | (d & 7);
          qkT[((size_t)b * 4096 + n) * 128 + ds] = f2bf(val);
        }
      }
  } else {
#pragma unroll
    for (int ot = 0; ot < 4; ot++)
#pragma unroll
      for (int rr = 0; rr < 4; rr++) {
        int d = R0 - 128 + ot * 16 + g * 4 + rr;
        float bias = bv[d];
#pragma unroll
        for (int nt2 = 0; nt2 < 4; nt2++) {
          int n = n0 + nt2 * 16 + lr;
          int c = n & 63;
          int cs = ((((c >> 3) ^ (d & 7)) & 7) << 3) | (c & 7);
          vws[((size_t)(b * 128 + d)) * 4096 + (n & ~63) + cs] =
              f2bf(acc[ot][nt2][rr] + bias);
        }
      }
  }
}

// ---------------- K4: flash attention, 32x32 swapped-QK^T, in-reg P --------
// grid 1024 = b(4) x qt(32, 128 q-rows) x sp(8, 512 kv). 4 waves, 32 q/wave.
// K/V tiles staged via global_load_lds double-buffer (1 barrier/iter).
// QK^T = mfma(K,Q) -> lane owns q-column; P->A frags via cvt_pk+permlane32.
__launch_bounds__(256, 2)
__global__ void k_attn(const unsigned short* __restrict__ qkT,
                       const unsigned short* __restrict__ vws,
                       unsigned short* __restrict__ pc, float* __restrict__ lsum) {
  __shared__ __align__(16) char smem[2][32768];  // [buf][K 16K | VT 16K]
  const float C1 = 0.12751744f;                  // (1/sqrt(128)) * log2(e)
  int p = blockIdx.x;
  int bid = (p & 7) * 128 + (p >> 3);            // XCD swizzle (1024 % 8 == 0)
  int sp = bid & 7, qt = (bid >> 3) & 31, b = bid >> 8;
  int kv0 = sp * 512;
  int t = threadIdx.x, wid = t >> 6, lane = t & 63;
  int l31 = lane & 31, hi = lane >> 5;
  int qrb = qt * 128 + wid * 32;
  const unsigned short* qk_b = qkT + (size_t)b * 524288;
  const char* kgb = (const char*)qk_b;
  const char* vgb = (const char*)(vws + (size_t)b * 524288);

  bool stk = (wid < 2);
  int ch0 = (wid & 1) * 8;
  const char* vsrc_base = vgb + (size_t)(lane >> 3) * 8192 + (lane & 7) * 16;

#define STAGE(BUF, MB)                                                         \
  {                                                                            \
    char* base_ = smem[BUF];                                                   \
    _Pragma("unroll")                                                          \
    for (int i_ = 0; i_ < 8; i_++) {                                           \
      int ch_ = ch0 + i_;                                                      \
      if (stk) {                                                               \
        const char* g_ = kgb + (size_t)(MB) * 256 + ch_ * 1024 + lane * 16;    \
        __builtin_amdgcn_global_load_lds(                                      \
            (const __attribute__((address_space(1))) unsigned int*)g_,         \
            (__attribute__((address_space(3))) unsigned int*)(base_ + ch_ * 1024), \
            16, 0, 0);                                                         \
      } else {                                                                 \
        const char* g_ = vsrc_base + (size_t)ch_ * 65536 + (size_t)(MB) * 2;   \
        __builtin_amdgcn_global_load_lds(                                      \
            (const __attribute__((address_space(1))) unsigned int*)g_,         \
            (__attribute__((address_space(3))) unsigned int*)(base_ + 16384 + ch_ * 1024), \
            16, 0, 0);                                                         \
      }                                                                        \
    }                                                                          \
  }

  STAGE(0, kv0)

  // Q B-frags: qf[kk] = Q[qrb+l31][k = kk*16 + 8*hi + e]
  short8 qf[8];
  {
    int row = qrb + l31;
    const unsigned short* qr = qk_b + (size_t)row * 128;
#pragma unroll
    for (int kk = 0; kk < 8; kk++)
      qf[kk] = *(const short8*)(qr + (((2 * kk + hi) ^ (row & 7)) << 3));
  }

  f32x16 acc[4];
#pragma unroll
  for (int dt = 0; dt < 4; dt++)
#pragma unroll
    for (int r = 0; r < 16; r++) acc[dt][r] = 0.f;
  float lacc = 0.f;

  __syncthreads();

#pragma unroll 1
  for (int it = 0; it < 8; ++it) {
    int cur = it & 1;
    if (it < 7) STAGE(cur ^ 1, kv0 + it * 64 + 64)
    const char* KL = smem[cur];
    const char* VL = smem[cur] + 16384;

    // ---- QK^T swapped: s = mfma(K, Q); D[row=kv][col=q] ----
    f32x16 s0, s1;
#pragma unroll
    for (int r = 0; r < 16; r++) { s0[r] = 0.f; s1[r] = 0.f; }
    __builtin_amdgcn_s_setprio(1);
#pragma unroll
    for (int kk = 0; kk < 8; kk++) {
      int cs = 2 * kk + hi;
      short8 kf0 = *(const short8*)(KL + l31 * 256 + ((cs ^ (l31 & 7)) << 4));
      short8 kf1 = *(const short8*)(KL + (32 + l31) * 256 + ((cs ^ (l31 & 7)) << 4));
      s0 = __builtin_amdgcn_mfma_f32_32x32x16_bf16(kf0, qf[kk], s0, 0, 0, 0);
      s1 = __builtin_amdgcn_mfma_f32_32x32x16_bf16(kf1, qf[kk], s1, 0, 0, 0);
    }
    __builtin_amdgcn_s_setprio(0);

    // ---- softmax (no-max exp2) + in-register P->A frags (T12) ----
    short8 pa[4];
#pragma unroll
    for (int ct = 0; ct < 2; ct++) {
      unsigned int w0[4], w1[4];
#pragma unroll
      for (int a = 0; a < 4; a++) {
        float v0 = ct ? s1[4 * a + 0] : s0[4 * a + 0];
        float v1 = ct ? s1[4 * a + 1] : s0[4 * a + 1];
        float v2 = ct ? s1[4 * a + 2] : s0[4 * a + 2];
        float v3 = ct ? s1[4 * a + 3] : s0[4 * a + 3];
        float p0 = __builtin_amdgcn_exp2f(v0 * C1);
        float p1 = __builtin_amdgcn_exp2f(v1 * C1);
        float p2 = __builtin_amdgcn_exp2f(v2 * C1);
        float p3 = __builtin_amdgcn_exp2f(v3 * C1);
        lacc += (p0 + p1) + (p2 + p3);
        w0[a] = cvtpk_bf16(p0, p1);
        w1[a] = cvtpk_bf16(p2, p3);
      }
#pragma unroll
      for (int k2 = 0; k2 < 2; k2++) {
        unsigned int xa = w0[2 * k2], ya = w0[2 * k2 + 1];
        unsigned int xb = w1[2 * k2], yb = w1[2 * k2 + 1];
        asm("v_permlane32_swap_b32 %0, %1" : "+v"(xa), "+v"(ya));
        asm("v_permlane32_swap_b32 %0, %1" : "+v"(xb), "+v"(yb));
        union { unsigned int u[4]; short8 s8; } pk_;
        pk_.u[0] = xa; pk_.u[1] = xb; pk_.u[2] = ya; pk_.u[3] = yb;
        pa[ct * 2 + k2] = pk_.s8;
      }
    }

    // ---- PV: O[q][d] += P·V ----
    __builtin_amdgcn_s_setprio(1);
#pragma unroll
    for (int ks = 0; ks < 4; ks++) {
      int cv = 2 * ks + hi;
#pragma unroll
      for (int dt = 0; dt < 4; dt++) {
        int d = dt * 32 + l31;
        short8 vb = *(const short8*)(VL + d * 128 + ((cv ^ (d & 7)) << 4));
        acc[dt] = __builtin_amdgcn_mfma_f32_32x32x16_bf16(pa[ks], vb, acc[dt], 0, 0, 0);
      }
    }
    __builtin_amdgcn_s_setprio(0);
    __syncthreads();
  }

  // ---- epilogue ----
  float lf = lacc + __shfl_xor(lacc, 32);

  // O -> wave-private LDS [32 q][272B], then coalesced 16B global stores
  char* OL = smem[0] + wid * 8704;
#pragma unroll
  for (int dt = 0; dt < 4; dt++)
#pragma unroll
    for (int r = 0; r < 16; r++) {
      int q = (r & 3) + 8 * (r >> 2) + 4 * hi;
      *(unsigned short*)(OL + q * 272 + (dt * 32 + l31) * 2) = f2bf(acc[dt][r]);
    }
  unsigned short* dst = pc + ((size_t)sp * 16384 + (size_t)b * 4096 + qrb) * 128;
#pragma unroll
  for (int j = 0; j < 8; j++) {
    int row = lane >> 1;
    int off = (lane & 1) * 128 + j * 16;
    short8 v = *(const short8*)(OL + row * 272 + off);
    *(short8*)((char*)dst + row * 256 + off) = v;
  }
  if (lane < 32) lsum[sp * 16384 + (size_t)b * 4096 + qrb + l31] = lf;
#undef STAGE
}

// ---------------- K5: fused merge + output projection (MFMA) ---------------
__launch_bounds__(256)
__global__ void k_mergeout(const unsigned short* __restrict__ pc,
                           const float* __restrict__ lsum,
                           const unsigned short* __restrict__ wwb,
                           const float* __restrict__ bw,
                           float* __restrict__ out) {
  __shared__ float inv_l[64];
  __shared__ __align__(16) unsigned short Bl[64 * 128];
  int bid = blockIdx.x;
  int nt = bid & 63, b = bid >> 6;
  int n0 = nt * 64;
  size_t gnb = (size_t)b * 4096 + n0;
  int t = threadIdx.x;

  if (t < 64) {
    float L = 0.f;
#pragma unroll
    for (int sp = 0; sp < 8; sp++) L += lsum[sp * 16384 + gnb + t];
    inv_l[t] = 1.f / L;
  }
  __syncthreads();

  {  // merge 32 values per thread: n = t&63, v = (t>>6)*32 ..
    int n = t & 63, vs = t >> 6;
    float o[32] = {};
#pragma unroll
    for (int sp = 0; sp < 8; sp++) {
      const unsigned short* src = pc + ((size_t)sp * 16384 + gnb + n) * 128 + vs * 32;
#pragma unroll
      for (int c = 0; c < 4; c++) {
        short8 pv = *(const short8*)(src + c * 8);
#pragma unroll
        for (int j = 0; j < 8; j++) o[c * 8 + j] += bf2f((unsigned short)pv[j]);
      }
    }
    float inv = inv_l[n];
    unsigned int* B32 = (unsigned int*)Bl;
#pragma unroll
    for (int jj = 0; jj < 16; jj++) {
      int v = vs * 32 + jj * 2;
      int kg = v >> 3;
      int kgp = (kg & 8) | ((kg ^ n) & 7);
      unsigned int pk = (unsigned int)f2bf(o[jj * 2] * inv) |
                        ((unsigned int)f2bf(o[jj * 2 + 1] * inv) << 16);
      B32[n * 64 + kgp * 4 + ((v & 7) >> 1)] = pk;
    }
  }
  __syncthreads();

  int wid = t >> 6, lane = t & 63, g = lane >> 4, lr = lane & 15;
  int o0 = wid * 64;
  short8 af[4][4];
#pragma unroll
  for (int ot = 0; ot < 4; ot++) {
    int o = o0 + ot * 16 + lr;
#pragma unroll
    for (int ks = 0; ks < 4; ks++)
      af[ot][ks] = *(const short8*)(wwb + (size_t)o * 128 + ks * 32 + g * 8);
  }
  f32x4 acc[4][4];
#pragma unroll
  for (int i = 0; i < 4; i++)
#pragma unroll
    for (int j = 0; j < 4; j++) acc[i][j] = (f32x4){0.f, 0.f, 0.f, 0.f};
#pragma unroll
  for (int nt2 = 0; nt2 < 4; nt2++) {
    short8 bfr[4];
#pragma unroll
    for (int ks = 0; ks < 4; ks++) {
      int kg = ks * 4 + g;
      int kgp = (kg & 8) | ((kg ^ lr) & 7);
      bfr[ks] = *(const short8*)(Bl + (nt2 * 16 + lr) * 128 + kgp * 8);
    }
#pragma unroll
    for (int ot = 0; ot < 4; ot++)
#pragma unroll
      for (int ks = 0; ks < 4; ks++)
        acc[ot][nt2] = __builtin_amdgcn_mfma_f32_16x16x32_bf16(af[ot][ks], bfr[ks],
                                                               acc[ot][nt2], 0, 0, 0);
  }
#pragma unroll
  for (int ot = 0; ot < 4; ot++)
#pragma unroll
    for (int r = 0; r < 4; r++) {
      int o = o0 + ot * 16 + g * 4 + r;
      float bias = bw[o];
#pragma unroll
      for (int nt2 = 0; nt2 < 4; nt2++)
        out[((size_t)(b * 256 + o)) * 4096 + n0 + nt2 * 16 + lr] = acc[ot][nt2][r] + bias;
    }
}

extern "C" void kernel_launch(void* const* d_in, const int* in_sizes, int n_in,
                              void* d_out, int out_size, void* d_ws, size_t ws_size,
                              hipStream_t stream) {
  const float* x  = (const float*)d_in[0];
  const float* Wk = (const float*)d_in[1];
  const float* bk = (const float*)d_in[2];
  const float* Wv = (const float*)d_in[3];
  const float* bv = (const float*)d_in[4];
  const float* Ww = (const float*)d_in[5];
  const float* bw = (const float*)d_in[6];
  const float* u  = (const float*)d_in[7];

  char* ws = (char*)d_ws;
  float* sig            = (float*)(ws + OFF_SIGMA);
  float* lsum           = (float*)(ws + OFF_ML);
  unsigned short* qkT   = (unsigned short*)(ws + OFF_QKT);
  unsigned short* vbuf  = (unsigned short*)(ws + OFF_V);
  unsigned short* wcat  = (unsigned short*)(ws + OFF_WCAT);
  unsigned short* xfb   = (unsigned short*)(ws + OFF_XFB);
  unsigned short* pc    = (unsigned short*)(ws + OFF_PC);
  float* out            = (float*)d_out;

  k_maxpool<<<8192, 256, 0, stream>>>(x, xfb);
  k_sigma<<<1, 256, 0, stream>>>(Wk, u, sig);
  k_prep<<<96, 256, 0, stream>>>(Ww, Wk, Wv, wcat);
  k_qkv<<<256, 256, 0, stream>>>(xfb, wcat, bk, bv, sig, qkT, vbuf);
  k_attn<<<1024, 256, 0, stream>>>(qkT, vbuf, pc, lsum);
  k_mergeout<<<256, 256, 0, stream>>>(pc, lsum, wcat, bw, out);
}

// Round 9
// 100.959 us; speedup vs baseline: 1.0859x; 1.0859x over previous
//
#include <hip/hip_runtime.h>

typedef __attribute__((ext_vector_type(8))) short short8;
typedef __attribute__((ext_vector_type(4))) float f32x4;
typedef __attribute__((ext_vector_type(16))) float f32x16;

// B=4, C=256, pooled N=4096, kc=vc=128, oc=256
static constexpr size_t OFF_SIGMA = 0;
static constexpr size_t OFF_ML    = 256;                        // float[4][16384] row-sums
static constexpr size_t OFF_QKT   = 1048576;                    // bf16 [4][4096][128] (col-swizzled)
static constexpr size_t OFF_V     = OFF_QKT + 4194304;          // bf16 [4][128][4096] (64-tile swizzled)
static constexpr size_t OFF_WCAT  = OFF_V + 4194304;            // bf16 Ww[256][128] | Wk[128][256] | Wv[128][256]
static constexpr size_t OFF_PC    = OFF_WCAT + 196608;          // bf16 [4][16384][128]

__device__ inline unsigned short f2bf(float f) {
  unsigned int u = __float_as_uint(f);
  unsigned int r = u + 0x7fffu + ((u >> 16) & 1u);
  return (unsigned short)(r >> 16);
}
__device__ inline float bf2f(unsigned short s) {
  return __uint_as_float(((unsigned int)s) << 16);
}
__device__ inline unsigned int cvtpk_bf16(float a, float b) {
  unsigned int r;
  asm("v_cvt_pk_bf16_f32 %0, %1, %2" : "=v"(r) : "v"(a), "v"(b));
  return r;
}

// ---------------- K1: init = sigma (block 96, LDS-cached) + weight prep ----
__launch_bounds__(256)
__global__ void k_init(const float* __restrict__ Ww, const float* __restrict__ Wk,
                       const float* __restrict__ Wv, const float* __restrict__ u,
                       unsigned short* __restrict__ wcat, float* __restrict__ sig) {
  __shared__ float WT[256][129];   // WT[c][k] = Wk[k][c]
  __shared__ float red[256];
  __shared__ float vsh[256];
  __shared__ float ush[128];
  int t = threadIdx.x;
  if (blockIdx.x < 96) {
    int i = (blockIdx.x * 256 + t) * 4;       // 98304 total
    const float* src = (i < 32768) ? (Ww + i) : (i < 65536) ? (Wk + i - 32768)
                                                            : (Wv + i - 65536);
    float4 w = *(const float4*)src;
    unsigned int lo = (unsigned int)f2bf(w.x) | ((unsigned int)f2bf(w.y) << 16);
    unsigned int hi = (unsigned int)f2bf(w.z) | ((unsigned int)f2bf(w.w) << 16);
    *(uint2*)(wcat + i) = make_uint2(lo, hi);
    return;
  }
  // ---- spectral-norm sigma, Wk cached in LDS (transposed, pad 129) ----
#pragma unroll
  for (int i = 0; i < 32; i++) {
    int idx = i * 1024 + t * 4;
    float4 w = *(const float4*)(Wk + idx);
    int k = idx >> 8, c = idx & 255;
    WT[c][k] = w.x; WT[c + 1][k] = w.y; WT[c + 2][k] = w.z; WT[c + 3][k] = w.w;
  }
  if (t < 128) ush[t] = u[t];
  __syncthreads();
  float acc = 0.f;
#pragma unroll 8
  for (int k = 0; k < 128; k++) acc += WT[t][k] * ush[k];
  vsh[t] = acc;
  red[t] = acc * acc;
  __syncthreads();
  for (int s = 128; s > 0; s >>= 1) { if (t < s) red[t] += red[t + s]; __syncthreads(); }
  float nrm = sqrtf(red[0]) + 1e-12f;
  float vn = vsh[t] / nrm;
  __syncthreads();
  vsh[t] = vn;
  __syncthreads();
  float acc2 = 0.f;
  if (t < 128) {
#pragma unroll 8
    for (int c = 0; c < 256; c++) acc2 += WT[c][t] * vsh[c];
  }
  red[t] = (t < 128) ? acc2 * acc2 : 0.f;
  __syncthreads();
  for (int s = 128; s > 0; s >>= 1) { if (t < s) red[t] += red[t + s]; __syncthreads(); }
  if (t == 0) {
    float s2v = red[0];
    sig[0] = s2v / (sqrtf(s2v) + 1e-12f);
  }
}

// ---------------- K2: fused maxpool + projections via MFMA -----------------
// grid 256 = b(4) x nt(64, 64 pooled n each). Reads x directly, pools inline
// into the swizzled LDS B-tile. wid<2 -> q rows (Wk/sigma+bk, qkT col-swz),
// wid>=2 -> v rows (Wv+bv, vws 64-tile swz).
__launch_bounds__(256)
__global__ void k_qkv(const float* __restrict__ x,
                      const unsigned short* __restrict__ wcat,
                      const float* __restrict__ bk, const float* __restrict__ bv,
                      const float* __restrict__ sig,
                      unsigned short* __restrict__ qkT, unsigned short* __restrict__ vws) {
  __shared__ __align__(16) unsigned short Bl[64 * 64];   // [n][64c], kg-XOR swizzle
  int bid = blockIdx.x;
  int nt = bid & 63, b = bid >> 6;
  int n0 = nt * 64;
  int t = threadIdx.x, wid = t >> 6, lane = t & 63, g = lane >> 4, lr = lane & 15;
  int R0 = wid * 64;
  bool isq = (wid < 2);
  const unsigned short* wb = isq ? (wcat + 32768 + (size_t)R0 * 256)
                                 : (wcat + 65536 + (size_t)(R0 - 128) * 256);
  f32x4 acc[4][4];
#pragma unroll
  for (int i = 0; i < 4; i++)
#pragma unroll
    for (int j = 0; j < 4; j++) acc[i][j] = (f32x4){0.f, 0.f, 0.f, 0.f};

  // pooling mapping: thread = (cc = t>>2 in [0,64), q4 = t&3); covers
  // pooled n = q4*16 + j (j 0..15) at channel c = ks4*64 + cc.
  int cc = t >> 2, q4 = t & 3;
  int d0p = n0 >> 8;
  int d1p = ((n0 >> 4) & 15) + q4;
  const float* xrow = x + ((size_t)(b * 256) << 15) + d0p * 2048 + d1p * 64;

  unsigned short pool[16];
#define POOLLOAD(C)                                                          \
  {                                                                          \
    const float* pr_ = xrow + (size_t)(C) * 32768;                           \
    _Pragma("unroll")                                                        \
    for (int k8 = 0; k8 < 8; k8++) {                                         \
      float4 a_ = *(const float4*)(pr_ + k8 * 4);                            \
      float4 b_ = *(const float4*)(pr_ + 32 + k8 * 4);                       \
      float4 c_ = *(const float4*)(pr_ + 1024 + k8 * 4);                     \
      float4 d_ = *(const float4*)(pr_ + 1056 + k8 * 4);                     \
      float p0_ = fmaxf(fmaxf(fmaxf(a_.x, a_.y), fmaxf(b_.x, b_.y)),         \
                        fmaxf(fmaxf(c_.x, c_.y), fmaxf(d_.x, d_.y)));        \
      float p1_ = fmaxf(fmaxf(fmaxf(a_.z, a_.w), fmaxf(b_.z, b_.w)),         \
                        fmaxf(fmaxf(c_.z, c_.w), fmaxf(d_.z, d_.w)));        \
      pool[k8 * 2] = f2bf(p0_);                                              \
      pool[k8 * 2 + 1] = f2bf(p1_);                                          \
    }                                                                        \
  }

  POOLLOAD(cc)

#pragma unroll 1
  for (int ks4 = 0; ks4 < 4; ks4++) {
    int k0 = ks4 * 64;
    __syncthreads();
#pragma unroll
    for (int j = 0; j < 16; j++) {
      int nn = q4 * 16 + j;
      Bl[nn * 64 + (((cc >> 3) ^ (nn & 7)) << 3) + (cc & 7)] = pool[j];
    }
    if (ks4 < 3) POOLLOAD(k0 + 64 + cc)
    __syncthreads();
#pragma unroll
    for (int ks2 = 0; ks2 < 2; ks2++) {
      short8 af[4], bf[4];
#pragma unroll
      for (int ot = 0; ot < 4; ot++)
        af[ot] = *(const short8*)(wb + (size_t)(ot * 16 + lr) * 256 + k0 + ks2 * 32 + g * 8);
#pragma unroll
      for (int nt2 = 0; nt2 < 4; nt2++) {
        int n = nt2 * 16 + lr;
        bf[nt2] = *(const short8*)(Bl + n * 64 + (((ks2 * 4 + g) ^ (n & 7)) << 3));
      }
#pragma unroll
      for (int ot = 0; ot < 4; ot++)
#pragma unroll
        for (int nt2 = 0; nt2 < 4; nt2++)
          acc[ot][nt2] = __builtin_amdgcn_mfma_f32_16x16x32_bf16(af[ot], bf[nt2],
                                                                 acc[ot][nt2], 0, 0, 0);
    }
  }
#undef POOLLOAD

  if (isq) {
    float inv_s = 1.0f / sig[0];
#pragma unroll
    for (int ot = 0; ot < 4; ot++)
#pragma unroll
      for (int rr = 0; rr < 4; rr++) {
        int d = R0 + ot * 16 + g * 4 + rr;
        float bias = bk[d];
#pragma unroll
        for (int nt2 = 0; nt2 < 4; nt2++) {
          int n = n0 + nt2 * 16 + lr;
          float val = acc[ot][nt2][rr] * inv_s + bias;
          int ds = ((((d >> 3) ^ (n & 7)) & 15) << 3) | (d & 7);
          qkT[((size_t)b * 4096 + n) * 128 + ds] = f2bf(val);
        }
      }
  } else {
#pragma unroll
    for (int ot = 0; ot < 4; ot++)
#pragma unroll
      for (int rr = 0; rr < 4; rr++) {
        int d = R0 - 128 + ot * 16 + g * 4 + rr;
        float bias = bv[d];
#pragma unroll
        for (int nt2 = 0; nt2 < 4; nt2++) {
          int n = n0 + nt2 * 16 + lr;
          int c = n & 63;
          int cs = ((((c >> 3) ^ (d & 7)) & 7) << 3) | (c & 7);
          vws[((size_t)(b * 128 + d)) * 4096 + (n & ~63) + cs] =
              f2bf(acc[ot][nt2][rr] + bias);
        }
      }
  }
}

// ---------------- K3: flash attention, 32x32 swapped-QK^T, in-reg P --------
// grid 512 = b(4) x qt(32, 128 q-rows) x sp(4, 1024 kv). 4 waves, 32 q/wave.
// K/V tiles staged via global_load_lds double-buffer (1 barrier/iter).
__launch_bounds__(256, 2)
__global__ void k_attn(const unsigned short* __restrict__ qkT,
                       const unsigned short* __restrict__ vws,
                       unsigned short* __restrict__ pc, float* __restrict__ lsum) {
  __shared__ __align__(16) char smem[2][32768];  // [buf][K 16K | V 16K]
  const float C1 = 0.12751744f;                  // (1/sqrt(128)) * log2(e)
  int p = blockIdx.x;
  int bid = (p & 7) * 64 + (p >> 3);             // XCD swizzle (512 % 8 == 0)
  int sp = bid & 3, qt = (bid >> 2) & 31, b = bid >> 7;
  int kv0 = sp * 1024;
  int t = threadIdx.x, wid = t >> 6, lane = t & 63;
  int l31 = lane & 31, hi = lane >> 5;
  int qrb = qt * 128 + wid * 32;
  const unsigned short* qk_b = qkT + (size_t)b * 524288;
  const char* kgb = (const char*)qk_b;
  const char* vgb = (const char*)(vws + (size_t)b * 524288);

  bool stk = (wid < 2);
  int ch0 = (wid & 1) * 8;
  const char* vsrc_base = vgb + (size_t)(lane >> 3) * 8192 + (lane & 7) * 16;

#define STAGE(BUF, MB)                                                         \
  {                                                                            \
    char* base_ = smem[BUF];                                                   \
    _Pragma("unroll")                                                          \
    for (int i_ = 0; i_ < 8; i_++) {                                           \
      int ch_ = ch0 + i_;                                                      \
      if (stk) {                                                               \
        const char* g_ = kgb + (size_t)(MB) * 256 + ch_ * 1024 + lane * 16;    \
        __builtin_amdgcn_global_load_lds(                                      \
            (const __attribute__((address_space(1))) unsigned int*)g_,         \
            (__attribute__((address_space(3))) unsigned int*)(base_ + ch_ * 1024), \
            16, 0, 0);                                                         \
      } else {                                                                 \
        const char* g_ = vsrc_base + (size_t)ch_ * 65536 + (size_t)(MB) * 2;   \
        __builtin_amdgcn_global_load_lds(                                      \
            (const __attribute__((address_space(1))) unsigned int*)g_,         \
            (__attribute__((address_space(3))) unsigned int*)(base_ + 16384 + ch_ * 1024), \
            16, 0, 0);                                                         \
      }                                                                        \
    }                                                                          \
  }

  STAGE(0, kv0)

  // Q B-frags: qf[kk] = Q[qrb+l31][k = kk*16 + 8*hi + e]
  short8 qf[8];
  {
    int row = qrb + l31;
    const unsigned short* qr = qk_b + (size_t)row * 128;
#pragma unroll
    for (int kk = 0; kk < 8; kk++)
      qf[kk] = *(const short8*)(qr + (((2 * kk + hi) ^ (row & 7)) << 3));
  }

  f32x16 acc[4];
#pragma unroll
  for (int dt = 0; dt < 4; dt++)
#pragma unroll
    for (int r = 0; r < 16; r++) acc[dt][r] = 0.f;
  float lacc = 0.f;

  __syncthreads();

#pragma unroll 1
  for (int it = 0; it < 16; ++it) {
    int cur = it & 1;
    if (it < 15) STAGE(cur ^ 1, kv0 + it * 64 + 64)
    const char* KL = smem[cur];
    const char* VL = smem[cur] + 16384;

    // ---- QK^T swapped: s = mfma(K, Q); D[row=kv][col=q] ----
    f32x16 s0, s1;
#pragma unroll
    for (int r = 0; r < 16; r++) { s0[r] = 0.f; s1[r] = 0.f; }
    __builtin_amdgcn_s_setprio(1);
#pragma unroll
    for (int kk = 0; kk < 8; kk++) {
      int cs = 2 * kk + hi;
      short8 kf0 = *(const short8*)(KL + l31 * 256 + ((cs ^ (l31 & 7)) << 4));
      short8 kf1 = *(const short8*)(KL + (32 + l31) * 256 + ((cs ^ (l31 & 7)) << 4));
      s0 = __builtin_amdgcn_mfma_f32_32x32x16_bf16(kf0, qf[kk], s0, 0, 0, 0);
      s1 = __builtin_amdgcn_mfma_f32_32x32x16_bf16(kf1, qf[kk], s1, 0, 0, 0);
    }
    __builtin_amdgcn_s_setprio(0);

    // ---- softmax (no-max exp2) + in-register P->A frags ----
    short8 pa[4];
#pragma unroll
    for (int ct = 0; ct < 2; ct++) {
      unsigned int w0[4], w1[4];
#pragma unroll
      for (int a = 0; a < 4; a++) {
        float v0 = ct ? s1[4 * a + 0] : s0[4 * a + 0];
        float v1 = ct ? s1[4 * a + 1] : s0[4 * a + 1];
        float v2 = ct ? s1[4 * a + 2] : s0[4 * a + 2];
        float v3 = ct ? s1[4 * a + 3] : s0[4 * a + 3];
        float p0 = __builtin_amdgcn_exp2f(v0 * C1);
        float p1 = __builtin_amdgcn_exp2f(v1 * C1);
        float p2 = __builtin_amdgcn_exp2f(v2 * C1);
        float p3 = __builtin_amdgcn_exp2f(v3 * C1);
        lacc += (p0 + p1) + (p2 + p3);
        w0[a] = cvtpk_bf16(p0, p1);
        w1[a] = cvtpk_bf16(p2, p3);
      }
#pragma unroll
      for (int k2 = 0; k2 < 2; k2++) {
        unsigned int xa = w0[2 * k2], ya = w0[2 * k2 + 1];
        unsigned int xb = w1[2 * k2], yb = w1[2 * k2 + 1];
        asm("v_permlane32_swap_b32 %0, %1" : "+v"(xa), "+v"(ya));
        asm("v_permlane32_swap_b32 %0, %1" : "+v"(xb), "+v"(yb));
        union { unsigned int u[4]; short8 s8; } pk_;
        pk_.u[0] = xa; pk_.u[1] = xb; pk_.u[2] = ya; pk_.u[3] = yb;
        pa[ct * 2 + k2] = pk_.s8;
      }
    }

    // ---- PV: O[q][d] += P·V ----
    __builtin_amdgcn_s_setprio(1);
#pragma unroll
    for (int ks = 0; ks < 4; ks++) {
      int cv = 2 * ks + hi;
#pragma unroll
      for (int dt = 0; dt < 4; dt++) {
        int d = dt * 32 + l31;
        short8 vb = *(const short8*)(VL + d * 128 + ((cv ^ (d & 7)) << 4));
        acc[dt] = __builtin_amdgcn_mfma_f32_32x32x16_bf16(pa[ks], vb, acc[dt], 0, 0, 0);
      }
    }
    __builtin_amdgcn_s_setprio(0);
    __syncthreads();
  }

  // ---- epilogue ----
  float lf = lacc + __shfl_xor(lacc, 32);

  char* OL = smem[0] + wid * 8704;
#pragma unroll
  for (int dt = 0; dt < 4; dt++)
#pragma unroll
    for (int r = 0; r < 16; r++) {
      int q = (r & 3) + 8 * (r >> 2) + 4 * hi;
      *(unsigned short*)(OL + q * 272 + (dt * 32 + l31) * 2) = f2bf(acc[dt][r]);
    }
  unsigned short* dst = pc + ((size_t)sp * 16384 + (size_t)b * 4096 + qrb) * 128;
#pragma unroll
  for (int j = 0; j < 8; j++) {
    int row = lane >> 1;
    int off = (lane & 1) * 128 + j * 16;
    short8 v = *(const short8*)(OL + row * 272 + off);
    *(short8*)((char*)dst + row * 256 + off) = v;
  }
  if (lane < 32) lsum[sp * 16384 + (size_t)b * 4096 + qrb + l31] = lf;
#undef STAGE
}

// ---------------- K4: fused merge + output projection (MFMA) ---------------
__launch_bounds__(256)
__global__ void k_mergeout(const unsigned short* __restrict__ pc,
                           const float* __restrict__ lsum,
                           const unsigned short* __restrict__ wwb,
                           const float* __restrict__ bw,
                           float* __restrict__ out) {
  __shared__ float inv_l[64];
  __shared__ __align__(16) unsigned short Bl[64 * 128];
  int bid = blockIdx.x;
  int nt = bid & 63, b = bid >> 6;
  int n0 = nt * 64;
  size_t gnb = (size_t)b * 4096 + n0;
  int t = threadIdx.x;

  if (t < 64) {
    float L = 0.f;
#pragma unroll
    for (int sp = 0; sp < 4; sp++) L += lsum[sp * 16384 + gnb + t];
    inv_l[t] = 1.f / L;
  }
  __syncthreads();

  {  // merge 32 values per thread: n = t&63, v = (t>>6)*32 ..
    int n = t & 63, vs = t >> 6;
    float o[32] = {};
#pragma unroll
    for (int sp = 0; sp < 4; sp++) {
      const unsigned short* src = pc + ((size_t)sp * 16384 + gnb + n) * 128 + vs * 32;
#pragma unroll
      for (int c = 0; c < 4; c++) {
        short8 pv = *(const short8*)(src + c * 8);
#pragma unroll
        for (int j = 0; j < 8; j++) o[c * 8 + j] += bf2f((unsigned short)pv[j]);
      }
    }
    float inv = inv_l[n];
    unsigned int* B32 = (unsigned int*)Bl;
#pragma unroll
    for (int jj = 0; jj < 16; jj++) {
      int v = vs * 32 + jj * 2;
      int kg = v >> 3;
      int kgp = (kg & 8) | ((kg ^ n) & 7);
      unsigned int pk = (unsigned int)f2bf(o[jj * 2] * inv) |
                        ((unsigned int)f2bf(o[jj * 2 + 1] * inv) << 16);
      B32[n * 64 + kgp * 4 + ((v & 7) >> 1)] = pk;
    }
  }
  __syncthreads();

  int wid = t >> 6, lane = t & 63, g = lane >> 4, lr = lane & 15;
  int o0 = wid * 64;
  short8 af[4][4];
#pragma unroll
  for (int ot = 0; ot < 4; ot++) {
    int o = o0 + ot * 16 + lr;
#pragma unroll
    for (int ks = 0; ks < 4; ks++)
      af[ot][ks] = *(const short8*)(wwb + (size_t)o * 128 + ks * 32 + g * 8);
  }
  f32x4 acc[4][4];
#pragma unroll
  for (int i = 0; i < 4; i++)
#pragma unroll
    for (int j = 0; j < 4; j++) acc[i][j] = (f32x4){0.f, 0.f, 0.f, 0.f};
#pragma unroll
  for (int nt2 = 0; nt2 < 4; nt2++) {
    short8 bfr[4];
#pragma unroll
    for (int ks = 0; ks < 4; ks++) {
      int kg = ks * 4 + g;
      int kgp = (kg & 8) | ((kg ^ lr) & 7);
      bfr[ks] = *(const short8*)(Bl + (nt2 * 16 + lr) * 128 + kgp * 8);
    }
#pragma unroll
    for (int ot = 0; ot < 4; ot++)
#pragma unroll
      for (int ks = 0; ks < 4; ks++)
        acc[ot][nt2] = __builtin_amdgcn_mfma_f32_16x16x32_bf16(af[ot][ks], bfr[ks],
                                                               acc[ot][nt2], 0, 0, 0);
  }
#pragma unroll
  for (int ot = 0; ot < 4; ot++)
#pragma unroll
    for (int r = 0; r < 4; r++) {
      int o = o0 + ot * 16 + g * 4 + r;
      float bias = bw[o];
#pragma unroll
      for (int nt2 = 0; nt2 < 4; nt2++)
        out[((size_t)(b * 256 + o)) * 4096 + n0 + nt2 * 16 + lr] = acc[ot][nt2][r] + bias;
    }
}

extern "C" void kernel_launch(void* const* d_in, const int* in_sizes, int n_in,
                              void* d_out, int out_size, void* d_ws, size_t ws_size,
                              hipStream_t stream) {
  const float* x  = (const float*)d_in[0];
  const float* Wk = (const float*)d_in[1];
  const float* bk = (const float*)d_in[2];
  const float* Wv = (const float*)d_in[3];
  const float* bv = (const float*)d_in[4];
  const float* Ww = (const float*)d_in[5];
  const float* bw = (const float*)d_in[6];
  const float* u  = (const float*)d_in[7];

  char* ws = (char*)d_ws;
  float* sig            = (float*)(ws + OFF_SIGMA);
  float* lsum           = (float*)(ws + OFF_ML);
  unsigned short* qkT   = (unsigned short*)(ws + OFF_QKT);
  unsigned short* vbuf  = (unsigned short*)(ws + OFF_V);
  unsigned short* wcat  = (unsigned short*)(ws + OFF_WCAT);
  unsigned short* pc    = (unsigned short*)(ws + OFF_PC);
  float* out            = (float*)d_out;

  k_init<<<97, 256, 0, stream>>>(Ww, Wk, Wv, u, wcat, sig);
  k_qkv<<<256, 256, 0, stream>>>(x, wcat, bk, bv, sig, qkT, vbuf);
  k_attn<<<512, 256, 0, stream>>>(qkT, vbuf, pc, lsum);
  k_mergeout<<<256, 256, 0, stream>>>(pc, lsum, wcat, bw, out);
}

// Round 11
// 92.305 us; speedup vs baseline: 1.1877x; 1.0938x over previous
//
#include <hip/hip_runtime.h>

typedef __attribute__((ext_vector_type(8))) short short8;
typedef __attribute__((ext_vector_type(4))) float f32x4;
typedef __attribute__((ext_vector_type(16))) float f32x16;

// B=4, C=256, pooled N=4096, kc=vc=128, oc=256
static constexpr size_t OFF_SIGMA = 0;
static constexpr size_t OFF_ML    = 256;                        // float[4][16384] row-sums
static constexpr size_t OFF_QKT   = 1048576;                    // bf16 [4][4096][128] (col-swizzled, pre-scaled by sqrt(C1))
static constexpr size_t OFF_V     = OFF_QKT + 4194304;          // bf16 [4][128][4096] (64-tile swizzled)
static constexpr size_t OFF_WCAT  = OFF_V + 4194304;            // bf16 Ww[256][128] | Wk[128][256] | Wv[128][256]
static constexpr size_t OFF_PC    = OFF_WCAT + 196608;          // bf16 [4][16384][128]

__device__ inline unsigned short f2bf(float f) {
  unsigned int u = __float_as_uint(f);
  unsigned int r = u + 0x7fffu + ((u >> 16) & 1u);
  return (unsigned short)(r >> 16);
}
__device__ inline float bf2f(unsigned short s) {
  return __uint_as_float(((unsigned int)s) << 16);
}
__device__ inline unsigned int cvtpk_bf16(float a, float b) {
  unsigned int r;
  asm("v_cvt_pk_bf16_f32 %0, %1, %2" : "=v"(r) : "v"(a), "v"(b));
  return r;
}

// ---------------- K1: init = sigma (block 96, LDS-cached) + weight prep ----
__launch_bounds__(256)
__global__ void k_init(const float* __restrict__ Ww, const float* __restrict__ Wk,
                       const float* __restrict__ Wv, const float* __restrict__ u,
                       unsigned short* __restrict__ wcat, float* __restrict__ sig) {
  __shared__ float WT[256][129];   // WT[c][k] = Wk[k][c]
  __shared__ float red[256];
  __shared__ float vsh[256];
  __shared__ float ush[128];
  int t = threadIdx.x;
  if (blockIdx.x < 96) {
    int i = (blockIdx.x * 256 + t) * 4;       // 98304 total
    const float* src = (i < 32768) ? (Ww + i) : (i < 65536) ? (Wk + i - 32768)
                                                            : (Wv + i - 65536);
    float4 w = *(const float4*)src;
    unsigned int lo = (unsigned int)f2bf(w.x) | ((unsigned int)f2bf(w.y) << 16);
    unsigned int hi = (unsigned int)f2bf(w.z) | ((unsigned int)f2bf(w.w) << 16);
    *(uint2*)(wcat + i) = make_uint2(lo, hi);
    return;
  }
  // ---- spectral-norm sigma, Wk cached in LDS (transposed, pad 129) ----
#pragma unroll
  for (int i = 0; i < 32; i++) {
    int idx = i * 1024 + t * 4;
    float4 w = *(const float4*)(Wk + idx);
    int k = idx >> 8, c = idx & 255;
    WT[c][k] = w.x; WT[c + 1][k] = w.y; WT[c + 2][k] = w.z; WT[c + 3][k] = w.w;
  }
  if (t < 128) ush[t] = u[t];
  __syncthreads();
  float acc = 0.f;
#pragma unroll 8
  for (int k = 0; k < 128; k++) acc += WT[t][k] * ush[k];
  vsh[t] = acc;
  red[t] = acc * acc;
  __syncthreads();
  for (int s = 128; s > 0; s >>= 1) { if (t < s) red[t] += red[t + s]; __syncthreads(); }
  float nrm = sqrtf(red[0]) + 1e-12f;
  float vn = vsh[t] / nrm;
  __syncthreads();
  vsh[t] = vn;
  __syncthreads();
  float acc2 = 0.f;
  if (t < 128) {
#pragma unroll 8
    for (int c = 0; c < 256; c++) acc2 += WT[c][t] * vsh[c];
  }
  red[t] = (t < 128) ? acc2 * acc2 : 0.f;
  __syncthreads();
  for (int s = 128; s > 0; s >>= 1) { if (t < s) red[t] += red[t + s]; __syncthreads(); }
  if (t == 0) {
    float s2v = red[0];
    sig[0] = s2v / (sqrtf(s2v) + 1e-12f);
  }
}

// ---------------- K2: fused maxpool + projections via MFMA (8 waves) -------
// grid 256 = b(4) x nt(64, 64 pooled n each). 512 threads. wid<4 -> q rows
// (store qkT col-swz, pre-scaled by sqrt(C1) -- Q and K share this buffer, so
// the QK^T product picks up exactly C1), wid>=4 -> v rows (vws 64-tile swz).
__launch_bounds__(512)
__global__ void k_qkv(const float* __restrict__ x,
                      const unsigned short* __restrict__ wcat,
                      const float* __restrict__ bk, const float* __restrict__ bv,
                      const float* __restrict__ sig,
                      unsigned short* __restrict__ qkT, unsigned short* __restrict__ vws) {
  __shared__ __align__(16) unsigned short Bl[64 * 64];   // [n][64c], kg-XOR swizzle
  const float SQC1 = 0.35709584f;                        // sqrt(log2(e)/sqrt(128))
  int bid = blockIdx.x;
  int nt = bid & 63, b = bid >> 6;
  int n0 = nt * 64;
  int t = threadIdx.x, wid = t >> 6, lane = t & 63, g = lane >> 4, lr = lane & 15;
  int R0 = wid * 32;
  bool isq = (wid < 4);
  const unsigned short* wb = isq ? (wcat + 32768 + (size_t)R0 * 256)
                                 : (wcat + 65536 + (size_t)(R0 - 128) * 256);
  f32x4 acc[2][4];
#pragma unroll
  for (int i = 0; i < 2; i++)
#pragma unroll
    for (int j = 0; j < 4; j++) acc[i][j] = (f32x4){0.f, 0.f, 0.f, 0.f};

  // pooling: thread = (cc = t>>3, q4 = (t>>1)&3, kh = t&1); 8 outputs
  int kh = t & 1, q4 = (t >> 1) & 3, cc = t >> 3;
  int d0p = n0 >> 8;
  int d1p = ((n0 >> 4) & 15) + q4;
  const float* xrow = x + ((size_t)(b * 256) << 15) + d0p * 2048 + d1p * 64 + kh * 16;

  unsigned short pool[8];
#define POOLLOAD(C)                                                          \
  {                                                                          \
    const float* pr_ = xrow + (size_t)(C) * 32768;                           \
    _Pragma("unroll")                                                        \
    for (int k8 = 0; k8 < 4; k8++) {                                         \
      float4 a_ = *(const float4*)(pr_ + k8 * 4);                            \
      float4 b_ = *(const float4*)(pr_ + 32 + k8 * 4);                       \
      float4 c_ = *(const float4*)(pr_ + 1024 + k8 * 4);                     \
      float4 d_ = *(const float4*)(pr_ + 1056 + k8 * 4);                     \
      float p0_ = fmaxf(fmaxf(fmaxf(a_.x, a_.y), fmaxf(b_.x, b_.y)),         \
                        fmaxf(fmaxf(c_.x, c_.y), fmaxf(d_.x, d_.y)));        \
      float p1_ = fmaxf(fmaxf(fmaxf(a_.z, a_.w), fmaxf(b_.z, b_.w)),         \
                        fmaxf(fmaxf(c_.z, c_.w), fmaxf(d_.z, d_.w)));        \
      pool[k8 * 2] = f2bf(p0_);                                              \
      pool[k8 * 2 + 1] = f2bf(p1_);                                          \
    }                                                                        \
  }

  POOLLOAD(cc)

#pragma unroll 1
  for (int ks4 = 0; ks4 < 4; ks4++) {
    int k0 = ks4 * 64;
    __syncthreads();
#pragma unroll
    for (int j = 0; j < 8; j++) {
      int nn = q4 * 16 + kh * 8 + j;
      Bl[nn * 64 + (((cc >> 3) ^ (nn & 7)) << 3) + (cc & 7)] = pool[j];
    }
    if (ks4 < 3) POOLLOAD(k0 + 64 + cc)
    __syncthreads();
#pragma unroll
    for (int ks2 = 0; ks2 < 2; ks2++) {
      short8 af[2], bf[4];
#pragma unroll
      for (int ot = 0; ot < 2; ot++)
        af[ot] = *(const short8*)(wb + (size_t)(ot * 16 + lr) * 256 + k0 + ks2 * 32 + g * 8);
#pragma unroll
      for (int nt2 = 0; nt2 < 4; nt2++) {
        int n = nt2 * 16 + lr;
        bf[nt2] = *(const short8*)(Bl + n * 64 + (((ks2 * 4 + g) ^ (n & 7)) << 3));
      }
#pragma unroll
      for (int ot = 0; ot < 2; ot++)
#pragma unroll
        for (int nt2 = 0; nt2 < 4; nt2++)
          acc[ot][nt2] = __builtin_amdgcn_mfma_f32_16x16x32_bf16(af[ot], bf[nt2],
                                                                 acc[ot][nt2], 0, 0, 0);
    }
  }
#undef POOLLOAD

  if (isq) {
    float s1c = SQC1 / sig[0];
#pragma unroll
    for (int ot = 0; ot < 2; ot++)
#pragma unroll
      for (int rr = 0; rr < 4; rr++) {
        int d = R0 + ot * 16 + g * 4 + rr;
        float bias = bk[d] * SQC1;
#pragma unroll
        for (int nt2 = 0; nt2 < 4; nt2++) {
          int n = n0 + nt2 * 16 + lr;
          float val = acc[ot][nt2][rr] * s1c + bias;
          int ds = ((((d >> 3) ^ (n & 7)) & 15) << 3) | (d & 7);
          qkT[((size_t)b * 4096 + n) * 128 + ds] = f2bf(val);
        }
      }
  } else {
#pragma unroll
    for (int ot = 0; ot < 2; ot++)
#pragma unroll
      for (int rr = 0; rr < 4; rr++) {
        int d = R0 - 128 + ot * 16 + g * 4 + rr;
        float bias = bv[d];
#pragma unroll
        for (int nt2 = 0; nt2 < 4; nt2++) {
          int n = n0 + nt2 * 16 + lr;
          int c = n & 63;
          int cs = ((((c >> 3) ^ (d & 7)) & 7) << 3) | (c & 7);
          vws[((size_t)(b * 128 + d)) * 4096 + (n & ~63) + cs] =
              f2bf(acc[ot][nt2][rr] + bias);
        }
      }
  }
}

// ---------------- K3: flash attention, precomputed LDS offsets -------------
// grid 512 = b(4) x qt(32, 128 q-rows) x sp(4, 1024 kv). 4 waves, 32 q/wave.
// gload_lds dbuf; 2-unrolled body folds buffer-select into ds offset imms.
// Scores arrive pre-scaled by C1 (sqrt(C1) on each operand) -> exp2 direct.
__launch_bounds__(256, 2)
__global__ void k_attn(const unsigned short* __restrict__ qkT,
                       const unsigned short* __restrict__ vws,
                       unsigned short* __restrict__ pc, float* __restrict__ lsum) {
  __shared__ __align__(16) char smem[2][32768];  // [buf][K 16K | V 16K]
  int p = blockIdx.x;
  int bid = (p & 7) * 64 + (p >> 3);             // XCD swizzle (512 % 8 == 0)
  int sp = bid & 3, qt = (bid >> 2) & 31, b = bid >> 7;
  int kv0 = sp * 1024;
  int t = threadIdx.x, wid = t >> 6, lane = t & 63;
  int l31 = lane & 31, hi = lane >> 5, e = l31 & 7;
  int qrb = qt * 128 + wid * 32;
  const unsigned short* qk_b = qkT + (size_t)b * 524288;
  const char* kgb = (const char*)qk_b;
  const char* vgb = (const char*)(vws + (size_t)b * 524288);
  const char* sbase = smem[0];

  bool stk = (wid < 2);
  int ch0 = (wid & 1) * 8;
  const char* vsrc_base = vgb + (size_t)(lane >> 3) * 8192 + (lane & 7) * 16;

#define STAGE(BUF, MB)                                                         \
  {                                                                            \
    char* base_ = smem[BUF];                                                   \
    _Pragma("unroll")                                                          \
    for (int i_ = 0; i_ < 8; i_++) {                                           \
      int ch_ = ch0 + i_;                                                      \
      if (stk) {                                                               \
        const char* g_ = kgb + (size_t)(MB) * 256 + ch_ * 1024 + lane * 16;    \
        __builtin_amdgcn_global_load_lds(                                      \
            (const __attribute__((address_space(1))) unsigned int*)g_,         \
            (__attribute__((address_space(3))) unsigned int*)(base_ + ch_ * 1024), \
            16, 0, 0);                                                         \
      } else {                                                                 \
        const char* g_ = vsrc_base + (size_t)ch_ * 65536 + (size_t)(MB) * 2;   \
        __builtin_amdgcn_global_load_lds(                                      \
            (const __attribute__((address_space(1))) unsigned int*)g_,         \
            (__attribute__((address_space(3))) unsigned int*)(base_ + 16384 + ch_ * 1024), \
            16, 0, 0);                                                         \
      }                                                                        \
    }                                                                          \
  }

  STAGE(0, kv0)

  // Q B-frags (pre-scaled by sqrt(C1) in k_qkv)
  short8 qf[8];
  {
    int row = qrb + l31;
    const unsigned short* qr = qk_b + (size_t)row * 128;
#pragma unroll
    for (int kk = 0; kk < 8; kk++)
      qf[kk] = *(const short8*)(qr + (((2 * kk + hi) ^ (row & 7)) << 3));
  }

  // precomputed LDS byte offsets (VGPR-resident; buffer/dt/row via imm)
  unsigned qoff[8], pvoff[4];
#pragma unroll
  for (int kk = 0; kk < 8; kk++) qoff[kk] = l31 * 256 + (((2 * kk + hi) ^ e) << 4);
#pragma unroll
  for (int ks = 0; ks < 4; ks++) pvoff[ks] = l31 * 128 + (((2 * ks + hi) ^ e) << 4);

  f32x16 acc[4];
#pragma unroll
  for (int dt = 0; dt < 4; dt++)
#pragma unroll
    for (int r = 0; r < 16; r++) acc[dt][r] = 0.f;
  float lacc = 0.f;

  __syncthreads();

#define ATTN_BODY(CUR, DO_STAGE, MBNEXT)                                       \
  {                                                                            \
    if (DO_STAGE) STAGE(CUR ^ 1, MBNEXT)                                       \
    f32x16 s0, s1;                                                             \
    _Pragma("unroll")                                                          \
    for (int r = 0; r < 16; r++) { s0[r] = 0.f; s1[r] = 0.f; }                 \
    __builtin_amdgcn_s_setprio(1);                                             \
    _Pragma("unroll")                                                          \
    for (int kk = 0; kk < 8; kk++) {                                           \
      short8 kf0 = *(const short8*)(sbase + (CUR) * 32768 + qoff[kk]);         \
      short8 kf1 = *(const short8*)(sbase + (CUR) * 32768 + 8192 + qoff[kk]);  \
      s0 = __builtin_amdgcn_mfma_f32_32x32x16_bf16(kf0, qf[kk], s0, 0, 0, 0);  \
      s1 = __builtin_amdgcn_mfma_f32_32x32x16_bf16(kf1, qf[kk], s1, 0, 0, 0);  \
    }                                                                          \
    __builtin_amdgcn_s_setprio(0);                                             \
    short8 pa[4];                                                              \
    _Pragma("unroll")                                                          \
    for (int ct = 0; ct < 2; ct++) {                                           \
      unsigned int w0[4], w1[4];                                               \
      _Pragma("unroll")                                                        \
      for (int a = 0; a < 4; a++) {                                            \
        float p0 = __builtin_amdgcn_exp2f(ct ? s1[4 * a + 0] : s0[4 * a + 0]); \
        float p1 = __builtin_amdgcn_exp2f(ct ? s1[4 * a + 1] : s0[4 * a + 1]); \
        float p2 = __builtin_amdgcn_exp2f(ct ? s1[4 * a + 2] : s0[4 * a + 2]); \
        float p3 = __builtin_amdgcn_exp2f(ct ? s1[4 * a + 3] : s0[4 * a + 3]); \
        lacc += (p0 + p1) + (p2 + p3);                                         \
        w0[a] = cvtpk_bf16(p0, p1);                                            \
        w1[a] = cvtpk_bf16(p2, p3);                                            \
      }                                                                        \
      _Pragma("unroll")                                                        \
      for (int k2 = 0; k2 < 2; k2++) {                                         \
        unsigned int xa = w0[2 * k2], ya = w0[2 * k2 + 1];                     \
        unsigned int xb = w1[2 * k2], yb = w1[2 * k2 + 1];                     \
        asm("v_permlane32_swap_b32 %0, %1" : "+v"(xa), "+v"(ya));              \
        asm("v_permlane32_swap_b32 %0, %1" : "+v"(xb), "+v"(yb));              \
        union { unsigned int u[4]; short8 s8; } pk_;                           \
        pk_.u[0] = xa; pk_.u[1] = xb; pk_.u[2] = ya; pk_.u[3] = yb;            \
        pa[ct * 2 + k2] = pk_.s8;                                              \
      }                                                                        \
    }                                                                          \
    __builtin_amdgcn_s_setprio(1);                                             \
    _Pragma("unroll")                                                          \
    for (int ks = 0; ks < 4; ks++) {                                           \
      _Pragma("unroll")                                                        \
      for (int dt = 0; dt < 4; dt++) {                                         \
        short8 vb = *(const short8*)(sbase + (CUR) * 32768 + 16384 +           \
                                     dt * 4096 + pvoff[ks]);                   \
        acc[dt] = __builtin_amdgcn_mfma_f32_32x32x16_bf16(pa[ks], vb, acc[dt], \
                                                          0, 0, 0);            \
      }                                                                        \
    }                                                                          \
    __builtin_amdgcn_s_setprio(0);                                             \
    __syncthreads();                                                           \
  }

#pragma unroll 1
  for (int it2 = 0; it2 < 8; ++it2) {
    int mb0 = kv0 + it2 * 128;
    ATTN_BODY(0, true, mb0 + 64)
    ATTN_BODY(1, (it2 < 7), mb0 + 128)
  }
#undef ATTN_BODY

  // ---- epilogue ----
  float lf = lacc + __shfl_xor(lacc, 32);

  char* OL = smem[0] + wid * 8704;
#pragma unroll
  for (int dt = 0; dt < 4; dt++)
#pragma unroll
    for (int r = 0; r < 16; r++) {
      int q = (r & 3) + 8 * (r >> 2) + 4 * hi;
      *(unsigned short*)(OL + q * 272 + (dt * 32 + l31) * 2) = f2bf(acc[dt][r]);
    }
  unsigned short* dst = pc + ((size_t)sp * 16384 + (size_t)b * 4096 + qrb) * 128;
#pragma unroll
  for (int j = 0; j < 8; j++) {
    int row = lane >> 1;
    int off = (lane & 1) * 128 + j * 16;
    short8 v = *(const short8*)(OL + row * 272 + off);
    *(short8*)((char*)dst + row * 256 + off) = v;
  }
  if (lane < 32) lsum[sp * 16384 + (size_t)b * 4096 + qrb + l31] = lf;
#undef STAGE
}

// ---------------- K4: fused merge + output projection (MFMA) ---------------
__launch_bounds__(256)
__global__ void k_mergeout(const unsigned short* __restrict__ pc,
                           const float* __restrict__ lsum,
                           const unsigned short* __restrict__ wwb,
                           const float* __restrict__ bw,
                           float* __restrict__ out) {
  __shared__ float inv_l[64];
  __shared__ __align__(16) unsigned short Bl[64 * 128];
  int bid = blockIdx.x;
  int nt = bid & 63, b = bid >> 6;
  int n0 = nt * 64;
  size_t gnb = (size_t)b * 4096 + n0;
  int t = threadIdx.x;

  if (t < 64) {
    float L = 0.f;
#pragma unroll
    for (int sp = 0; sp < 4; sp++) L += lsum[sp * 16384 + gnb + t];
    inv_l[t] = 1.f / L;
  }
  __syncthreads();

  {  // merge 32 values per thread: n = t&63, v = (t>>6)*32 ..
    int n = t & 63, vs = t >> 6;
    float o[32] = {};
#pragma unroll
    for (int sp = 0; sp < 4; sp++) {
      const unsigned short* src = pc + ((size_t)sp * 16384 + gnb + n) * 128 + vs * 32;
#pragma unroll
      for (int c = 0; c < 4; c++) {
        short8 pv = *(const short8*)(src + c * 8);
#pragma unroll
        for (int j = 0; j < 8; j++) o[c * 8 + j] += bf2f((unsigned short)pv[j]);
      }
    }
    float inv = inv_l[n];
    unsigned int* B32 = (unsigned int*)Bl;
#pragma unroll
    for (int jj = 0; jj < 16; jj++) {
      int v = vs * 32 + jj * 2;
      int kg = v >> 3;
      int kgp = (kg & 8) | ((kg ^ n) & 7);
      unsigned int pk = (unsigned int)f2bf(o[jj * 2] * inv) |
                        ((unsigned int)f2bf(o[jj * 2 + 1] * inv) << 16);
      B32[n * 64 + kgp * 4 + ((v & 7) >> 1)] = pk;
    }
  }
  __syncthreads();

  int wid = t >> 6, lane = t & 63, g = lane >> 4, lr = lane & 15;
  int o0 = wid * 64;
  short8 af[4][4];
#pragma unroll
  for (int ot = 0; ot < 4; ot++) {
    int o = o0 + ot * 16 + lr;
#pragma unroll
    for (int ks = 0; ks < 4; ks++)
      af[ot][ks] = *(const short8*)(wwb + (size_t)o * 128 + ks * 32 + g * 8);
  }
  f32x4 acc[4][4];
#pragma unroll
  for (int i = 0; i < 4; i++)
#pragma unroll
    for (int j = 0; j < 4; j++) acc[i][j] = (f32x4){0.f, 0.f, 0.f, 0.f};
#pragma unroll
  for (int nt2 = 0; nt2 < 4; nt2++) {
    short8 bfr[4];
#pragma unroll
    for (int ks = 0; ks < 4; ks++) {
      int kg = ks * 4 + g;
      int kgp = (kg & 8) | ((kg ^ lr) & 7);
      bfr[ks] = *(const short8*)(Bl + (nt2 * 16 + lr) * 128 + kgp * 8);
    }
#pragma unroll
    for (int ot = 0; ot < 4; ot++)
#pragma unroll
      for (int ks = 0; ks < 4; ks++)
        acc[ot][nt2] = __builtin_amdgcn_mfma_f32_16x16x32_bf16(af[ot][ks], bfr[ks],
                                                               acc[ot][nt2], 0, 0, 0);
  }
#pragma unroll
  for (int ot = 0; ot < 4; ot++)
#pragma unroll
    for (int r = 0; r < 4; r++) {
      int o = o0 + ot * 16 + g * 4 + r;
      float bias = bw[o];
#pragma unroll
      for (int nt2 = 0; nt2 < 4; nt2++)
        out[((size_t)(b * 256 + o)) * 4096 + n0 + nt2 * 16 + lr] = acc[ot][nt2][r] + bias;
    }
}

extern "C" void kernel_launch(void* const* d_in, const int* in_sizes, int n_in,
                              void* d_out, int out_size, void* d_ws, size_t ws_size,
                              hipStream_t stream) {
  const float* x  = (const float*)d_in[0];
  const float* Wk = (const float*)d_in[1];
  const float* bk = (const float*)d_in[2];
  const float* Wv = (const float*)d_in[3];
  const float* bv = (const float*)d_in[4];
  const float* Ww = (const float*)d_in[5];
  const float* bw = (const float*)d_in[6];
  const float* u  = (const float*)d_in[7];

  char* ws = (char*)d_ws;
  float* sig            = (float*)(ws + OFF_SIGMA);
  float* lsum           = (float*)(ws + OFF_ML);
  unsigned short* qkT   = (unsigned short*)(ws + OFF_QKT);
  unsigned short* vbuf  = (unsigned short*)(ws + OFF_V);
  unsigned short* wcat  = (unsigned short*)(ws + OFF_WCAT);
  unsigned short* pc    = (unsigned short*)(ws + OFF_PC);
  float* out            = (float*)d_out;

  k_init<<<97, 256, 0, stream>>>(Ww, Wk, Wv, u, wcat, sig);
  k_qkv<<<256, 512, 0, stream>>>(x, wcat, bk, bv, sig, qkT, vbuf);
  k_attn<<<512, 256, 0, stream>>>(qkT, vbuf, pc, lsum);
  k_mergeout<<<256, 256, 0, stream>>>(pc, lsum, wcat, bw, out);
}

// Round 14
// 91.939 us; speedup vs baseline: 1.1924x; 1.0040x over previous
//
#include <hip/hip_runtime.h>

typedef __attribute__((ext_vector_type(8))) short short8;
typedef __attribute__((ext_vector_type(4))) float f32x4;
typedef __attribute__((ext_vector_type(16))) float f32x16;

// B=4, C=256, pooled N=4096, kc=vc=128, oc=256
static constexpr size_t OFF_SIGMA = 0;
static constexpr size_t OFF_ML    = 256;                        // float[4][16384] row-sums
static constexpr size_t OFF_QKT   = 1048576;                    // bf16 [4][4096][128] (col-swizzled, pre-scaled by sqrt(C1))
static constexpr size_t OFF_V     = OFF_QKT + 4194304;          // bf16 [4][128][4096] (64-tile swizzled)
static constexpr size_t OFF_WCAT  = OFF_V + 4194304;            // bf16 Ww[256][128] | Wk[128][256] | Wv[128][256]
static constexpr size_t OFF_PC    = OFF_WCAT + 196608;          // bf16 [4][16384][128]

__device__ inline unsigned short f2bf(float f) {
  unsigned int u = __float_as_uint(f);
  unsigned int r = u + 0x7fffu + ((u >> 16) & 1u);
  return (unsigned short)(r >> 16);
}
__device__ inline float bf2f(unsigned short s) {
  return __uint_as_float(((unsigned int)s) << 16);
}
__device__ inline unsigned int cvtpk_bf16(float a, float b) {
  unsigned int r;
  asm("v_cvt_pk_bf16_f32 %0, %1, %2" : "=v"(r) : "v"(a), "v"(b));
  return r;
}

// ---------------- K1: init = sigma (block 96, LDS-cached) + weight prep ----
__launch_bounds__(256)
__global__ void k_init(const float* __restrict__ Ww, const float* __restrict__ Wk,
                       const float* __restrict__ Wv, const float* __restrict__ u,
                       unsigned short* __restrict__ wcat, float* __restrict__ sig) {
  __shared__ float WT[256][129];   // WT[c][k] = Wk[k][c]
  __shared__ float red[256];
  __shared__ float vsh[256];
  __shared__ float ush[128];
  int t = threadIdx.x;
  if (blockIdx.x < 96) {
    int i = (blockIdx.x * 256 + t) * 4;       // 98304 total
    const float* src = (i < 32768) ? (Ww + i) : (i < 65536) ? (Wk + i - 32768)
                                                            : (Wv + i - 65536);
    float4 w = *(const float4*)src;
    unsigned int lo = (unsigned int)f2bf(w.x) | ((unsigned int)f2bf(w.y) << 16);
    unsigned int hi = (unsigned int)f2bf(w.z) | ((unsigned int)f2bf(w.w) << 16);
    *(uint2*)(wcat + i) = make_uint2(lo, hi);
    return;
  }
  // ---- spectral-norm sigma, Wk cached in LDS (transposed, pad 129) ----
#pragma unroll
  for (int i = 0; i < 32; i++) {
    int idx = i * 1024 + t * 4;
    float4 w = *(const float4*)(Wk + idx);
    int k = idx >> 8, c = idx & 255;
    WT[c][k] = w.x; WT[c + 1][k] = w.y; WT[c + 2][k] = w.z; WT[c + 3][k] = w.w;
  }
  if (t < 128) ush[t] = u[t];
  __syncthreads();
  float acc = 0.f;
#pragma unroll 8
  for (int k = 0; k < 128; k++) acc += WT[t][k] * ush[k];
  vsh[t] = acc;
  red[t] = acc * acc;
  __syncthreads();
  for (int s = 128; s > 0; s >>= 1) { if (t < s) red[t] += red[t + s]; __syncthreads(); }
  float nrm = sqrtf(red[0]) + 1e-12f;
  float vn = vsh[t] / nrm;
  __syncthreads();
  vsh[t] = vn;
  __syncthreads();
  float acc2 = 0.f;
  if (t < 128) {
#pragma unroll 8
    for (int c = 0; c < 256; c++) acc2 += WT[c][t] * vsh[c];
  }
  red[t] = (t < 128) ? acc2 * acc2 : 0.f;
  __syncthreads();
  for (int s = 128; s > 0; s >>= 1) { if (t < s) red[t] += red[t + s]; __syncthreads(); }
  if (t == 0) {
    float s2v = red[0];
    sig[0] = s2v / (sqrtf(s2v) + 1e-12f);
  }
}

// ---------------- K2: fused maxpool + projections via MFMA (8 waves) -------
__launch_bounds__(512)
__global__ void k_qkv(const float* __restrict__ x,
                      const unsigned short* __restrict__ wcat,
                      const float* __restrict__ bk, const float* __restrict__ bv,
                      const float* __restrict__ sig,
                      unsigned short* __restrict__ qkT, unsigned short* __restrict__ vws) {
  __shared__ __align__(16) unsigned short Bl[64 * 64];   // [n][64c], kg-XOR swizzle
  const float SQC1 = 0.35709584f;                        // sqrt(log2(e)/sqrt(128))
  int bid = blockIdx.x;
  int nt = bid & 63, b = bid >> 6;
  int n0 = nt * 64;
  int t = threadIdx.x, wid = t >> 6, lane = t & 63, g = lane >> 4, lr = lane & 15;
  int R0 = wid * 32;
  bool isq = (wid < 4);
  const unsigned short* wb = isq ? (wcat + 32768 + (size_t)R0 * 256)
                                 : (wcat + 65536 + (size_t)(R0 - 128) * 256);
  f32x4 acc[2][4];
#pragma unroll
  for (int i = 0; i < 2; i++)
#pragma unroll
    for (int j = 0; j < 4; j++) acc[i][j] = (f32x4){0.f, 0.f, 0.f, 0.f};

  int kh = t & 1, q4 = (t >> 1) & 3, cc = t >> 3;
  int d0p = n0 >> 8;
  int d1p = ((n0 >> 4) & 15) + q4;
  const float* xrow = x + ((size_t)(b * 256) << 15) + d0p * 2048 + d1p * 64 + kh * 16;

  unsigned short pool[8];
#define POOLLOAD(C)                                                          \
  {                                                                          \
    const float* pr_ = xrow + (size_t)(C) * 32768;                           \
    _Pragma("unroll")                                                        \
    for (int k8 = 0; k8 < 4; k8++) {                                         \
      float4 a_ = *(const float4*)(pr_ + k8 * 4);                            \
      float4 b_ = *(const float4*)(pr_ + 32 + k8 * 4);                       \
      float4 c_ = *(const float4*)(pr_ + 1024 + k8 * 4);                     \
      float4 d_ = *(const float4*)(pr_ + 1056 + k8 * 4);                     \
      float p0_ = fmaxf(fmaxf(fmaxf(a_.x, a_.y), fmaxf(b_.x, b_.y)),         \
                        fmaxf(fmaxf(c_.x, c_.y), fmaxf(d_.x, d_.y)));        \
      float p1_ = fmaxf(fmaxf(fmaxf(a_.z, a_.w), fmaxf(b_.z, b_.w)),         \
                        fmaxf(fmaxf(c_.z, c_.w), fmaxf(d_.z, d_.w)));        \
      pool[k8 * 2] = f2bf(p0_);                                              \
      pool[k8 * 2 + 1] = f2bf(p1_);                                          \
    }                                                                        \
  }

  POOLLOAD(cc)

#pragma unroll 1
  for (int ks4 = 0; ks4 < 4; ks4++) {
    int k0 = ks4 * 64;
    __syncthreads();
#pragma unroll
    for (int j = 0; j < 8; j++) {
      int nn = q4 * 16 + kh * 8 + j;
      Bl[nn * 64 + (((cc >> 3) ^ (nn & 7)) << 3) + (cc & 7)] = pool[j];
    }
    if (ks4 < 3) POOLLOAD(k0 + 64 + cc)
    __syncthreads();
#pragma unroll
    for (int ks2 = 0; ks2 < 2; ks2++) {
      short8 af[2], bf[4];
#pragma unroll
      for (int ot = 0; ot < 2; ot++)
        af[ot] = *(const short8*)(wb + (size_t)(ot * 16 + lr) * 256 + k0 + ks2 * 32 + g * 8);
#pragma unroll
      for (int nt2 = 0; nt2 < 4; nt2++) {
        int n = nt2 * 16 + lr;
        bf[nt2] = *(const short8*)(Bl + n * 64 + (((ks2 * 4 + g) ^ (n & 7)) << 3));
      }
#pragma unroll
      for (int ot = 0; ot < 2; ot++)
#pragma unroll
        for (int nt2 = 0; nt2 < 4; nt2++)
          acc[ot][nt2] = __builtin_amdgcn_mfma_f32_16x16x32_bf16(af[ot], bf[nt2],
                                                                 acc[ot][nt2], 0, 0, 0);
    }
  }
#undef POOLLOAD

  if (isq) {
    float s1c = SQC1 / sig[0];
#pragma unroll
    for (int ot = 0; ot < 2; ot++)
#pragma unroll
      for (int rr = 0; rr < 4; rr++) {
        int d = R0 + ot * 16 + g * 4 + rr;
        float bias = bk[d] * SQC1;
#pragma unroll
        for (int nt2 = 0; nt2 < 4; nt2++) {
          int n = n0 + nt2 * 16 + lr;
          float val = acc[ot][nt2][rr] * s1c + bias;
          int ds = ((((d >> 3) ^ (n & 7)) & 15) << 3) | (d & 7);
          qkT[((size_t)b * 4096 + n) * 128 + ds] = f2bf(val);
        }
      }
  } else {
#pragma unroll
    for (int ot = 0; ot < 2; ot++)
#pragma unroll
      for (int rr = 0; rr < 4; rr++) {
        int d = R0 - 128 + ot * 16 + g * 4 + rr;
        float bias = bv[d];
#pragma unroll
        for (int nt2 = 0; nt2 < 4; nt2++) {
          int n = n0 + nt2 * 16 + lr;
          int c = n & 63;
          int cs = ((((c >> 3) ^ (d & 7)) & 7) << 3) | (c & 7);
          vws[((size_t)(b * 128 + d)) * 4096 + (n & ~63) + cs] =
              f2bf(acc[ot][nt2][rr] + bias);
        }
      }
  }
}

// ---------------- K3: flash attention, precomputed LDS offsets (R11) -------
// grid 512 = b(4) x qt(32, 128 q-rows) x sp(4, 1024 kv). 4 waves, 32 q/wave.
// gload_lds dbuf; 2-unrolled body folds buffer-select into ds offset imms.
// Scores arrive pre-scaled by C1 (sqrt(C1) on each operand) -> exp2 direct.
__launch_bounds__(256, 2)
__global__ void k_attn(const unsigned short* __restrict__ qkT,
                       const unsigned short* __restrict__ vws,
                       unsigned short* __restrict__ pc, float* __restrict__ lsum) {
  __shared__ __align__(16) char smem[2][32768];  // [buf][K 16K | V 16K]
  int p = blockIdx.x;
  int bid = (p & 7) * 64 + (p >> 3);             // XCD swizzle (512 % 8 == 0)
  int sp = bid & 3, qt = (bid >> 2) & 31, b = bid >> 7;
  int kv0 = sp * 1024;
  int t = threadIdx.x, wid = t >> 6, lane = t & 63;
  int l31 = lane & 31, hi = lane >> 5, e = l31 & 7;
  int qrb = qt * 128 + wid * 32;
  const unsigned short* qk_b = qkT + (size_t)b * 524288;
  const char* kgb = (const char*)qk_b;
  const char* vgb = (const char*)(vws + (size_t)b * 524288);
  const char* sbase = smem[0];

  bool stk = (wid < 2);
  int ch0 = (wid & 1) * 8;
  const char* vsrc_base = vgb + (size_t)(lane >> 3) * 8192 + (lane & 7) * 16;

#define STAGE(BUF, MB)                                                         \
  {                                                                            \
    char* base_ = smem[BUF];                                                   \
    _Pragma("unroll")                                                          \
    for (int i_ = 0; i_ < 8; i_++) {                                           \
      int ch_ = ch0 + i_;                                                      \
      if (stk) {                                                               \
        const char* g_ = kgb + (size_t)(MB) * 256 + ch_ * 1024 + lane * 16;    \
        __builtin_amdgcn_global_load_lds(                                      \
            (const __attribute__((address_space(1))) unsigned int*)g_,         \
            (__attribute__((address_space(3))) unsigned int*)(base_ + ch_ * 1024), \
            16, 0, 0);                                                         \
      } else {                                                                 \
        const char* g_ = vsrc_base + (size_t)ch_ * 65536 + (size_t)(MB) * 2;   \
        __builtin_amdgcn_global_load_lds(                                      \
            (const __attribute__((address_space(1))) unsigned int*)g_,         \
            (__attribute__((address_space(3))) unsigned int*)(base_ + 16384 + ch_ * 1024), \
            16, 0, 0);                                                         \
      }                                                                        \
    }                                                                          \
  }

  STAGE(0, kv0)

  // Q B-frags (pre-scaled by sqrt(C1) in k_qkv)
  short8 qf[8];
  {
    int row = qrb + l31;
    const unsigned short* qr = qk_b + (size_t)row * 128;
#pragma unroll
    for (int kk = 0; kk < 8; kk++)
      qf[kk] = *(const short8*)(qr + (((2 * kk + hi) ^ (row & 7)) << 3));
  }

  // precomputed LDS byte offsets (VGPR-resident; buffer/dt/row via imm)
  unsigned qoff[8], pvoff[4];
#pragma unroll
  for (int kk = 0; kk < 8; kk++) qoff[kk] = l31 * 256 + (((2 * kk + hi) ^ e) << 4);
#pragma unroll
  for (int ks = 0; ks < 4; ks++) pvoff[ks] = l31 * 128 + (((2 * ks + hi) ^ e) << 4);

  f32x16 acc[4];
#pragma unroll
  for (int dt = 0; dt < 4; dt++)
#pragma unroll
    for (int r = 0; r < 16; r++) acc[dt][r] = 0.f;
  float lacc = 0.f;

  __syncthreads();

#define ATTN_BODY(CUR, DO_STAGE, MBNEXT)                                       \
  {                                                                            \
    if (DO_STAGE) STAGE(CUR ^ 1, MBNEXT)                                       \
    f32x16 s0, s1;                                                             \
    _Pragma("unroll")                                                          \
    for (int r = 0; r < 16; r++) { s0[r] = 0.f; s1[r] = 0.f; }                 \
    __builtin_amdgcn_s_setprio(1);                                             \
    _Pragma("unroll")                                                          \
    for (int kk = 0; kk < 8; kk++) {                                           \
      short8 kf0 = *(const short8*)(sbase + (CUR) * 32768 + qoff[kk]);         \
      short8 kf1 = *(const short8*)(sbase + (CUR) * 32768 + 8192 + qoff[kk]);  \
      s0 = __builtin_amdgcn_mfma_f32_32x32x16_bf16(kf0, qf[kk], s0, 0, 0, 0);  \
      s1 = __builtin_amdgcn_mfma_f32_32x32x16_bf16(kf1, qf[kk], s1, 0, 0, 0);  \
    }                                                                          \
    __builtin_amdgcn_s_setprio(0);                                             \
    short8 pa[4];                                                              \
    _Pragma("unroll")                                                          \
    for (int ct = 0; ct < 2; ct++) {                                           \
      unsigned int w0[4], w1[4];                                               \
      _Pragma("unroll")                                                        \
      for (int a = 0; a < 4; a++) {                                            \
        float p0 = __builtin_amdgcn_exp2f(ct ? s1[4 * a + 0] : s0[4 * a + 0]); \
        float p1 = __builtin_amdgcn_exp2f(ct ? s1[4 * a + 1] : s0[4 * a + 1]); \
        float p2 = __builtin_amdgcn_exp2f(ct ? s1[4 * a + 2] : s0[4 * a + 2]); \
        float p3 = __builtin_amdgcn_exp2f(ct ? s1[4 * a + 3] : s0[4 * a + 3]); \
        lacc += (p0 + p1) + (p2 + p3);                                         \
        w0[a] = cvtpk_bf16(p0, p1);                                            \
        w1[a] = cvtpk_bf16(p2, p3);                                            \
      }                                                                        \
      _Pragma("unroll")                                                        \
      for (int k2 = 0; k2 < 2; k2++) {                                         \
        unsigned int xa = w0[2 * k2], ya = w0[2 * k2 + 1];                     \
        unsigned int xb = w1[2 * k2], yb = w1[2 * k2 + 1];                     \
        asm("v_permlane32_swap_b32 %0, %1" : "+v"(xa), "+v"(ya));              \
        asm("v_permlane32_swap_b32 %0, %1" : "+v"(xb), "+v"(yb));              \
        union { unsigned int u[4]; short8 s8; } pk_;                           \
        pk_.u[0] = xa; pk_.u[1] = xb; pk_.u[2] = ya; pk_.u[3] = yb;            \
        pa[ct * 2 + k2] = pk_.s8;                                              \
      }                                                                        \
    }                                                                          \
    __builtin_amdgcn_s_setprio(1);                                             \
    _Pragma("unroll")                                                          \
    for (int ks = 0; ks < 4; ks++) {                                           \
      _Pragma("unroll")                                                        \
      for (int dt = 0; dt < 4; dt++) {                                         \
        short8 vb = *(const short8*)(sbase + (CUR) * 32768 + 16384 +           \
                                     dt * 4096 + pvoff[ks]);                   \
        acc[dt] = __builtin_amdgcn_mfma_f32_32x32x16_bf16(pa[ks], vb, acc[dt], \
                                                          0, 0, 0);            \
      }                                                                        \
    }                                                                          \
    __builtin_amdgcn_s_setprio(0);                                             \
    __syncthreads();                                                           \
  }

#pragma unroll 1
  for (int it2 = 0; it2 < 8; ++it2) {
    int mb0 = kv0 + it2 * 128;
    ATTN_BODY(0, true, mb0 + 64)
    ATTN_BODY(1, (it2 < 7), mb0 + 128)
  }
#undef ATTN_BODY

  // ---- epilogue ----
  float lf = lacc + __shfl_xor(lacc, 32);

  char* OL = smem[0] + wid * 8704;
#pragma unroll
  for (int dt = 0; dt < 4; dt++)
#pragma unroll
    for (int r = 0; r < 16; r++) {
      int q = (r & 3) + 8 * (r >> 2) + 4 * hi;
      *(unsigned short*)(OL + q * 272 + (dt * 32 + l31) * 2) = f2bf(acc[dt][r]);
    }
  unsigned short* dst = pc + ((size_t)sp * 16384 + (size_t)b * 4096 + qrb) * 128;
#pragma unroll
  for (int j = 0; j < 8; j++) {
    int row = lane >> 1;
    int off = (lane & 1) * 128 + j * 16;
    short8 v = *(const short8*)(OL + row * 272 + off);
    *(short8*)((char*)dst + row * 256 + off) = v;
  }
  if (lane < 32) lsum[sp * 16384 + (size_t)b * 4096 + qrb + l31] = lf;
#undef STAGE
}

// ---------------- K4: fused merge + output projection (MFMA, 512 thr) ------
// grid 256 = b(4) x nt(64, 64 n each). 8 waves: merge phase repartitioned
// (each thread 16 v-values), MFMA phase 8 waves x 32 o-rows.
__launch_bounds__(512)
__global__ void k_mergeout(const unsigned short* __restrict__ pc,
                           const float* __restrict__ lsum,
                           const unsigned short* __restrict__ wwb,
                           const float* __restrict__ bw,
                           float* __restrict__ out) {
  __shared__ float inv_l[64];
  __shared__ __align__(16) unsigned short Bl[64 * 128];
  int bid = blockIdx.x;
  int nt = bid & 63, b = bid >> 6;
  int n0 = nt * 64;
  size_t gnb = (size_t)b * 4096 + n0;
  int t = threadIdx.x;

  if (t < 64) {
    float L = 0.f;
#pragma unroll
    for (int sp = 0; sp < 4; sp++) L += lsum[sp * 16384 + gnb + t];
    inv_l[t] = 1.f / L;
  }
  __syncthreads();

  {  // merge 16 values per thread: n = t&63, v-range = (t>>6)*16 ..
    int n = t & 63, vs = t >> 6;
    float o[16] = {};
#pragma unroll
    for (int sp = 0; sp < 4; sp++) {
      const unsigned short* src = pc + ((size_t)sp * 16384 + gnb + n) * 128 + vs * 16;
#pragma unroll
      for (int c = 0; c < 2; c++) {
        short8 pv = *(const short8*)(src + c * 8);
#pragma unroll
        for (int j = 0; j < 8; j++) o[c * 8 + j] += bf2f((unsigned short)pv[j]);
      }
    }
    float inv = inv_l[n];
    unsigned int* B32 = (unsigned int*)Bl;
#pragma unroll
    for (int jj = 0; jj < 8; jj++) {
      int v = vs * 16 + jj * 2;
      int kg = v >> 3;
      int kgp = (kg & 8) | ((kg ^ n) & 7);
      unsigned int pk = (unsigned int)f2bf(o[jj * 2] * inv) |
                        ((unsigned int)f2bf(o[jj * 2 + 1] * inv) << 16);
      B32[n * 64 + kgp * 4 + ((v & 7) >> 1)] = pk;
    }
  }
  __syncthreads();

  int wid = t >> 6, lane = t & 63, g = lane >> 4, lr = lane & 15;
  int o0 = wid * 32;
  short8 af[2][4];
#pragma unroll
  for (int ot = 0; ot < 2; ot++) {
    int o = o0 + ot * 16 + lr;
#pragma unroll
    for (int ks = 0; ks < 4; ks++)
      af[ot][ks] = *(const short8*)(wwb + (size_t)o * 128 + ks * 32 + g * 8);
  }
  f32x4 acc[2][4];
#pragma unroll
  for (int i = 0; i < 2; i++)
#pragma unroll
    for (int j = 0; j < 4; j++) acc[i][j] = (f32x4){0.f, 0.f, 0.f, 0.f};
#pragma unroll
  for (int nt2 = 0; nt2 < 4; nt2++) {
    short8 bfr[4];
#pragma unroll
    for (int ks = 0; ks < 4; ks++) {
      int kg = ks * 4 + g;
      int kgp = (kg & 8) | ((kg ^ lr) & 7);
      bfr[ks] = *(const short8*)(Bl + (nt2 * 16 + lr) * 128 + kgp * 8);
    }
#pragma unroll
    for (int ot = 0; ot < 2; ot++)
#pragma unroll
      for (int ks = 0; ks < 4; ks++)
        acc[ot][nt2] = __builtin_amdgcn_mfma_f32_16x16x32_bf16(af[ot][ks], bfr[ks],
                                                               acc[ot][nt2], 0, 0, 0);
  }
#pragma unroll
  for (int ot = 0; ot < 2; ot++)
#pragma unroll
    for (int r = 0; r < 4; r++) {
      int o = o0 + ot * 16 + g * 4 + r;
      float bias = bw[o];
#pragma unroll
      for (int nt2 = 0; nt2 < 4; nt2++)
        out[((size_t)(b * 256 + o)) * 4096 + n0 + nt2 * 16 + lr] = acc[ot][nt2][r] + bias;
    }
}

extern "C" void kernel_launch(void* const* d_in, const int* in_sizes, int n_in,
                              void* d_out, int out_size, void* d_ws, size_t ws_size,
                              hipStream_t stream) {
  const float* x  = (const float*)d_in[0];
  const float* Wk = (const float*)d_in[1];
  const float* bk = (const float*)d_in[2];
  const float* Wv = (const float*)d_in[3];
  const float* bv = (const float*)d_in[4];
  const float* Ww = (const float*)d_in[5];
  const float* bw = (const float*)d_in[6];
  const float* u  = (const float*)d_in[7];

  char* ws = (char*)d_ws;
  float* sig            = (float*)(ws + OFF_SIGMA);
  float* lsum           = (float*)(ws + OFF_ML);
  unsigned short* qkT   = (unsigned short*)(ws + OFF_QKT);
  unsigned short* vbuf  = (unsigned short*)(ws + OFF_V);
  unsigned short* wcat  = (unsigned short*)(ws + OFF_WCAT);
  unsigned short* pc    = (unsigned short*)(ws + OFF_PC);
  float* out            = (float*)d_out;

  k_init<<<97, 256, 0, stream>>>(Ww, Wk, Wv, u, wcat, sig);
  k_qkv<<<256, 512, 0, stream>>>(x, wcat, bk, bv, sig, qkT, vbuf);
  k_attn<<<512, 256, 0, stream>>>(qkT, vbuf, pc, lsum);
  k_mergeout<<<256, 512, 0, stream>>>(pc, lsum, wcat, bw, out);
}